// Round 1
// baseline (576.410 us; speedup 1.0000x reference)
//
#include <hip/hip_runtime.h>
#include <math.h>

#define BB 8
#define NN 512
#define FF 128
#define TT 32
#define DD 64
constexpr float EPS = 1e-6f;

// ---------------- Stage 1: z[b][t][n][d] = tanh(sum_f x[b,n,f,t]*W[d,f] + bias[d]) ----------------
// grid: B * (N/4) = 1024 blocks, 256 threads
// LDS: xs[4][32][132] (x transposed to [t][f], padded stride 132 for 16B-aligned b128) + Wt[128][64]
__global__ __launch_bounds__(256) void z_kernel(const float* __restrict__ x,
                                                const float* __restrict__ W,
                                                const float* __restrict__ bias,
                                                float* __restrict__ z) {
    extern __shared__ float lds[];
    float* xs = lds;                      // 4*32*132 = 16896 floats
    float* Wt = lds + 4 * 32 * 132;      // 128*64 = 8192 floats
    const int tid = threadIdx.x;
    const int b  = blockIdx.x >> 7;       // 128 blocks per b
    const int n0 = (blockIdx.x & 127) * 4;

    // Load W[64][128] transposed -> Wt[f][d] (stride 64)
    const float4* W4 = (const float4*)W;
    #pragma unroll
    for (int it = 0; it < 8; ++it) {
        int idx4 = tid + it * 256;        // 2048 float4 total
        float4 w = W4[idx4];
        int d = idx4 >> 5;
        int f = (idx4 & 31) * 4;
        Wt[(f + 0) * 64 + d] = w.x;
        Wt[(f + 1) * 64 + d] = w.y;
        Wt[(f + 2) * 64 + d] = w.z;
        Wt[(f + 3) * 64 + d] = w.w;
    }
    // Load x[b][n0..n0+3][F][T] (contiguous 16384 floats), transpose to xs[ns][t][f]
    const float4* x4 = (const float4*)(x + ((size_t)b * NN + n0) * FF * TT);
    #pragma unroll
    for (int it = 0; it < 16; ++it) {
        int idx4 = tid + it * 256;        // 4096 float4 total
        float4 v = x4[idx4];
        int e   = idx4 * 4;
        int ns  = e >> 12;
        int rem = e & 4095;
        int f   = rem >> 5;
        int t   = rem & 31;               // multiple of 4
        float* base = xs + ns * (32 * 132) + t * 132 + f;
        base[0 * 132] = v.x;
        base[1 * 132] = v.y;
        base[2 * 132] = v.z;
        base[3 * 132] = v.w;
    }
    __syncthreads();

    const int t  = tid >> 3;              // 0..31
    const int d0 = (tid & 7) * 8;         // 0..56
    float acc[4][8];
    #pragma unroll
    for (int ns = 0; ns < 4; ++ns)
        #pragma unroll
        for (int dd = 0; dd < 8; ++dd) acc[ns][dd] = 0.f;

    #pragma unroll 4
    for (int fc = 0; fc < FF; fc += 4) {
        float wv[4][8];
        #pragma unroll
        for (int k = 0; k < 4; ++k) {
            float4 a = *(const float4*)&Wt[(fc + k) * 64 + d0];
            float4 c = *(const float4*)&Wt[(fc + k) * 64 + d0 + 4];
            wv[k][0] = a.x; wv[k][1] = a.y; wv[k][2] = a.z; wv[k][3] = a.w;
            wv[k][4] = c.x; wv[k][5] = c.y; wv[k][6] = c.z; wv[k][7] = c.w;
        }
        #pragma unroll
        for (int ns = 0; ns < 4; ++ns) {
            float4 xv = *(const float4*)&xs[ns * (32 * 132) + t * 132 + fc];
            float xk[4] = {xv.x, xv.y, xv.z, xv.w};
            #pragma unroll
            for (int dd = 0; dd < 8; ++dd) {
                acc[ns][dd] += xk[0] * wv[0][dd] + xk[1] * wv[1][dd]
                             + xk[2] * wv[2][dd] + xk[3] * wv[3][dd];
            }
        }
    }

    float bb[8];
    #pragma unroll
    for (int dd = 0; dd < 8; ++dd) bb[dd] = bias[d0 + dd];

    float* zb = z + (((size_t)b * TT + t) * NN + n0) * DD + d0;
    #pragma unroll
    for (int ns = 0; ns < 4; ++ns) {
        float4 o0, o1;
        o0.x = tanhf(acc[ns][0] + bb[0]);
        o0.y = tanhf(acc[ns][1] + bb[1]);
        o0.z = tanhf(acc[ns][2] + bb[2]);
        o0.w = tanhf(acc[ns][3] + bb[3]);
        o1.x = tanhf(acc[ns][4] + bb[4]);
        o1.y = tanhf(acc[ns][5] + bb[5]);
        o1.z = tanhf(acc[ns][6] + bb[6]);
        o1.w = tanhf(acc[ns][7] + bb[7]);
        *(float4*)(zb + (size_t)ns * DD)     = o0;
        *(float4*)(zb + (size_t)ns * DD + 4) = o1;
    }
}

// ---------------- Stage 2: att + normalize + mean over b ----------------
// grid: T * (N/32) = 512 blocks, 256 threads. Thread tile 8 rows x 8 cols.
// LDS: zs[512][64] fp32, XOR-swizzled in 16B units (u ^= (row>>3)&7) + sqv[512] + nv[512]
__global__ __launch_bounds__(256) void att_kernel(const float* __restrict__ z,
                                                  float* __restrict__ out) {
    extern __shared__ float lds[];
    float* zs  = lds;                 // 32768 floats (swizzled)
    float* sqv = lds + NN * DD;       // 512
    float* nv  = sqv + NN;            // 512
    const int tid = threadIdx.x;
    const int t   = blockIdx.x >> 4;
    const int n0  = (blockIdx.x & 15) * 32;
    const int tr  = tid >> 6;         // wave id = row group (8 rows)
    const int tc  = tid & 63;         // col group (8 cols)

    float acc[8][8];
    #pragma unroll
    for (int i = 0; i < 8; ++i)
        #pragma unroll
        for (int j = 0; j < 8; ++j) acc[i][j] = 0.f;

    for (int b = 0; b < BB; ++b) {
        __syncthreads();
        // stage z[b][t][*][*] into swizzled LDS: 8192 float4
        const float4* zsrc = (const float4*)(z + ((size_t)b * TT + t) * NN * DD);
        #pragma unroll
        for (int it = 0; it < 32; ++it) {
            int idx4 = tid + it * 256;
            float4 v = zsrc[idx4];
            int row = idx4 >> 4;                  // 16 units per row
            int u   = idx4 & 15;
            int us  = u ^ ((row >> 3) & 7);
            *(float4*)&zs[row * 64 + us * 4] = v;
        }
        __syncthreads();
        // squared norms / norms (2 rows per thread)
        #pragma unroll
        for (int k = 0; k < 2; ++k) {
            int r = tid * 2 + k;
            int sw = (r >> 3) & 7;
            float s = 0.f;
            #pragma unroll
            for (int u = 0; u < 16; ++u) {
                float4 v = *(const float4*)&zs[r * 64 + (u ^ sw) * 4];
                s += v.x * v.x + v.y * v.y + v.z * v.z + v.w * v.w;
            }
            sqv[r] = s;
            nv[r]  = sqrtf(s) + EPS;
        }
        __syncthreads();

        // dot[i][j] = z[n0+tr*8+i] . z[tc*8+j]
        float dot[8][8];
        #pragma unroll
        for (int i = 0; i < 8; ++i)
            #pragma unroll
            for (int j = 0; j < 8; ++j) dot[i][j] = 0.f;

        const int swm = tc & 7;   // (m>>3)&7 where m = tc*8+j, j<8
        #pragma unroll
        for (int dc = 0; dc < 16; ++dc) {
            float4 zr[8];
            #pragma unroll
            for (int i = 0; i < 8; ++i) {
                int r = n0 + tr * 8 + i;
                zr[i] = *(const float4*)&zs[r * 64 + (dc ^ ((r >> 3) & 7)) * 4];
            }
            #pragma unroll
            for (int j = 0; j < 8; ++j) {
                int m = tc * 8 + j;
                float4 zm = *(const float4*)&zs[m * 64 + (dc ^ swm) * 4];
                #pragma unroll
                for (int i = 0; i < 8; ++i) {
                    dot[i][j] += zr[i].x * zm.x + zr[i].y * zm.y
                               + zr[i].z * zm.z + zr[i].w * zm.w;
                }
            }
        }

        // epilogue: att = exp(cos - diff/sum), row-sum, normalize, accumulate
        float sqr[8], nr[8], sqm[8], nm[8];
        #pragma unroll
        for (int i = 0; i < 8; ++i) {
            int r = n0 + tr * 8 + i;
            sqr[i] = sqv[r]; nr[i] = nv[r];
        }
        #pragma unroll
        for (int j = 0; j < 8; ++j) {
            int m = tc * 8 + j;
            sqm[j] = sqv[m]; nm[j] = nv[m];
        }
        float rs[8];
        #pragma unroll
        for (int i = 0; i < 8; ++i) rs[i] = 0.f;
        #pragma unroll
        for (int i = 0; i < 8; ++i) {
            #pragma unroll
            for (int j = 0; j < 8; ++j) {
                float d   = dot[i][j];
                float cs  = __fdividef(d, nr[i] * nm[j]);
                float d2  = fmaxf(sqr[i] + sqm[j] - 2.f * d, 0.f);
                float dn  = sqrtf(d2);
                float a   = __expf(cs - __fdividef(dn, nr[i] + nm[j] + EPS));
                dot[i][j] = a;        // overwrite to save registers
                rs[i] += a;
            }
        }
        #pragma unroll
        for (int i = 0; i < 8; ++i) {
            float s = rs[i];
            s += __shfl_xor(s, 32);
            s += __shfl_xor(s, 16);
            s += __shfl_xor(s, 8);
            s += __shfl_xor(s, 4);
            s += __shfl_xor(s, 2);
            s += __shfl_xor(s, 1);
            float rinv = __fdividef(1.f, s + EPS);
            #pragma unroll
            for (int j = 0; j < 8; ++j) acc[i][j] += dot[i][j] * rinv;
        }
    }

    // write out[t][n0+tr*8+i][tc*8+j]
    #pragma unroll
    for (int i = 0; i < 8; ++i) {
        float4 o0, o1;
        o0.x = acc[i][0] * 0.125f;
        o0.y = acc[i][1] * 0.125f;
        o0.z = acc[i][2] * 0.125f;
        o0.w = acc[i][3] * 0.125f;
        o1.x = acc[i][4] * 0.125f;
        o1.y = acc[i][5] * 0.125f;
        o1.z = acc[i][6] * 0.125f;
        o1.w = acc[i][7] * 0.125f;
        float* op = out + ((size_t)t * NN + n0 + tr * 8 + i) * NN + tc * 8;
        *(float4*)op       = o0;
        *(float4*)(op + 4) = o1;
    }
}

extern "C" void kernel_launch(void* const* d_in, const int* in_sizes, int n_in,
                              void* d_out, int out_size, void* d_ws, size_t ws_size,
                              hipStream_t stream) {
    const float* x    = (const float*)d_in[0];
    const float* W    = (const float*)d_in[1];
    const float* bias = (const float*)d_in[2];
    float* out = (float*)d_out;
    float* z   = (float*)d_ws;   // B*T*N*D floats = 33.5 MB

    // Stage 1: 100352 B dynamic LDS
    z_kernel<<<dim3(BB * (NN / 4)), dim3(256), 100352, stream>>>(x, W, bias, z);
    // Stage 2: (512*64 + 2*512)*4 = 135168 B dynamic LDS
    att_kernel<<<dim3(TT * (NN / 32)), dim3(256), 135168, stream>>>(z, out);
}

// Round 2
// 243.545 us; speedup vs baseline: 2.3667x; 2.3667x over previous
//
#include <hip/hip_runtime.h>
#include <math.h>

#define BB 8
#define NN 512
#define FF 128
#define TT 32
#define DD 64
constexpr float EPS = 1e-6f;

typedef _Float16 half8 __attribute__((ext_vector_type(8)));
typedef float f32x4 __attribute__((ext_vector_type(4)));

// ---------------- Stage 1: z = tanh(x @ W^T + b); emit fp16 hi/lo split + fp32 sq/norm ----------------
// grid: B * (N/4) = 1024 blocks, 256 threads
__global__ __launch_bounds__(256) void z_kernel(const float* __restrict__ x,
                                                const float* __restrict__ W,
                                                const float* __restrict__ bias,
                                                _Float16* __restrict__ zh,
                                                _Float16* __restrict__ zl,
                                                float* __restrict__ sqv,
                                                float* __restrict__ nvv) {
    extern __shared__ float lds[];
    float* xs = lds;                      // 4*32*132 floats
    float* Wt = lds + 4 * 32 * 132;       // 128*64 floats
    const int tid = threadIdx.x;
    const int b  = blockIdx.x >> 7;
    const int n0 = (blockIdx.x & 127) * 4;

    const float4* W4 = (const float4*)W;
    #pragma unroll
    for (int it = 0; it < 8; ++it) {
        int idx4 = tid + it * 256;
        float4 w = W4[idx4];
        int d = idx4 >> 5;
        int f = (idx4 & 31) * 4;
        Wt[(f + 0) * 64 + d] = w.x;
        Wt[(f + 1) * 64 + d] = w.y;
        Wt[(f + 2) * 64 + d] = w.z;
        Wt[(f + 3) * 64 + d] = w.w;
    }
    const float4* x4 = (const float4*)(x + ((size_t)b * NN + n0) * FF * TT);
    #pragma unroll
    for (int it = 0; it < 16; ++it) {
        int idx4 = tid + it * 256;
        float4 v = x4[idx4];
        int e   = idx4 * 4;
        int ns  = e >> 12;
        int rem = e & 4095;
        int f   = rem >> 5;
        int t   = rem & 31;
        float* base = xs + ns * (32 * 132) + t * 132 + f;
        base[0 * 132] = v.x;
        base[1 * 132] = v.y;
        base[2 * 132] = v.z;
        base[3 * 132] = v.w;
    }
    __syncthreads();

    const int t  = tid >> 3;
    const int d0 = (tid & 7) * 8;
    float acc[4][8];
    #pragma unroll
    for (int ns = 0; ns < 4; ++ns)
        #pragma unroll
        for (int dd = 0; dd < 8; ++dd) acc[ns][dd] = 0.f;

    #pragma unroll 4
    for (int fc = 0; fc < FF; fc += 4) {
        float wv[4][8];
        #pragma unroll
        for (int k = 0; k < 4; ++k) {
            float4 a = *(const float4*)&Wt[(fc + k) * 64 + d0];
            float4 c = *(const float4*)&Wt[(fc + k) * 64 + d0 + 4];
            wv[k][0] = a.x; wv[k][1] = a.y; wv[k][2] = a.z; wv[k][3] = a.w;
            wv[k][4] = c.x; wv[k][5] = c.y; wv[k][6] = c.z; wv[k][7] = c.w;
        }
        #pragma unroll
        for (int ns = 0; ns < 4; ++ns) {
            float4 xv = *(const float4*)&xs[ns * (32 * 132) + t * 132 + fc];
            float xk[4] = {xv.x, xv.y, xv.z, xv.w};
            #pragma unroll
            for (int dd = 0; dd < 8; ++dd) {
                acc[ns][dd] += xk[0] * wv[0][dd] + xk[1] * wv[1][dd]
                             + xk[2] * wv[2][dd] + xk[3] * wv[3][dd];
            }
        }
    }

    float bb[8];
    #pragma unroll
    for (int dd = 0; dd < 8; ++dd) bb[dd] = bias[d0 + dd];

    const size_t zbase = ((size_t)b * TT + t) * NN + n0;   // row index base
    float sqp[4];
    #pragma unroll
    for (int ns = 0; ns < 4; ++ns) {
        half8 hv, lv;
        float sp = 0.f;
        #pragma unroll
        for (int dd = 0; dd < 8; ++dd) {
            float zf = tanhf(acc[ns][dd] + bb[dd]);
            sp += zf * zf;
            _Float16 h = (_Float16)zf;
            hv[dd] = h;
            lv[dd] = (_Float16)(zf - (float)h);
        }
        size_t off = (zbase + ns) * DD + d0;
        *(half8*)(zh + off) = hv;
        *(half8*)(zl + off) = lv;
        sqp[ns] = sp;
    }
    // reduce sq over the 8 d-group threads (consecutive lanes)
    #pragma unroll
    for (int k = 1; k < 8; k <<= 1) {
        #pragma unroll
        for (int ns = 0; ns < 4; ++ns) sqp[ns] += __shfl_xor(sqp[ns], k);
    }
    if ((tid & 7) == 0) {
        #pragma unroll
        for (int ns = 0; ns < 4; ++ns) {
            sqv[zbase + ns] = sqp[ns];
            nvv[zbase + ns] = sqrtf(sqp[ns]) + EPS;
        }
    }
}

// ---------------- Stage 2: S = Z Z^T via split-fp16 MFMA, epilogue, normalize, mean over b ----------------
// grid: 512 blocks (t = bid&31, rowtile = bid>>5), 512 threads = 8 waves.
// wave w: rows n0..n0+31 (2 MFMA tiles), cols w*64..w*64+63 (4 col-tiles).
__global__ __launch_bounds__(512, 3) void att2_kernel(const _Float16* __restrict__ zh,
                                                      const _Float16* __restrict__ zl,
                                                      const float* __restrict__ sqv,
                                                      const float* __restrict__ nvv,
                                                      float* __restrict__ out) {
    __shared__ float nv_s[2][NN];
    __shared__ float sq_s[2][NN];
    __shared__ float rs_s[2][8][32];
    const int tid  = threadIdx.x;
    const int w    = tid >> 6;
    const int lane = tid & 63;
    const int l15  = lane & 15;
    const int g    = lane >> 4;
    const int t    = blockIdx.x & 31;
    const int n0   = (blockIdx.x >> 5) * 32;

    float acc[4][2][4];
    #pragma unroll
    for (int ct = 0; ct < 4; ++ct)
        #pragma unroll
        for (int tt = 0; tt < 2; ++tt)
            #pragma unroll
            for (int ri = 0; ri < 4; ++ri) acc[ct][tt][ri] = 0.f;

    for (int b = 0; b < BB; ++b) {
        const int p = b & 1;
        const size_t nbase = ((size_t)b * TT + t) * NN;
        const size_t slab  = nbase * DD;
        nv_s[p][tid] = nvv[nbase + tid];
        sq_s[p][tid] = sqv[nbase + tid];

        // A fragments: rows n0 + tt*16 + (lane&15), k = s*32 + (lane>>4)*8 + i
        half8 ah[2][2], al[2][2];
        #pragma unroll
        for (int tt = 0; tt < 2; ++tt) {
            const size_t ro = slab + (size_t)(n0 + tt * 16 + l15) * DD + g * 8;
            ah[tt][0] = *(const half8*)(zh + ro);
            ah[tt][1] = *(const half8*)(zh + ro + 32);
            al[tt][0] = *(const half8*)(zl + ro);
            al[tt][1] = *(const half8*)(zl + ro + 32);
        }
        __syncthreads();

        float nr[2][4], sq_r[2][4], nri[2][4];
        #pragma unroll
        for (int tt = 0; tt < 2; ++tt)
            #pragma unroll
            for (int ri = 0; ri < 4; ++ri) {
                int row = n0 + tt * 16 + g * 4 + ri;
                nr[tt][ri]   = nv_s[p][row];
                sq_r[tt][ri] = sq_s[p][row];
                nri[tt][ri]  = __fdividef(1.f, nr[tt][ri]);
            }

        float att[4][2][4];
        float rs[2][4] = {{0.f,0.f,0.f,0.f},{0.f,0.f,0.f,0.f}};
        #pragma unroll
        for (int ct = 0; ct < 4; ++ct) {
            const int col = w * 64 + ct * 16 + l15;
            const size_t co = slab + (size_t)col * DD + g * 8;
            half8 bh0 = *(const half8*)(zh + co);
            half8 bh1 = *(const half8*)(zh + co + 32);
            half8 bl0 = *(const half8*)(zl + co);
            half8 bl1 = *(const half8*)(zl + co + 32);
            float nm  = nv_s[p][col];
            float sqm = sq_s[p][col];
            float nmi = __fdividef(1.f, nm);
            #pragma unroll
            for (int tt = 0; tt < 2; ++tt) {
                f32x4 d = {0.f, 0.f, 0.f, 0.f};
                d = __builtin_amdgcn_mfma_f32_16x16x32_f16(ah[tt][0], bh0, d, 0, 0, 0);
                d = __builtin_amdgcn_mfma_f32_16x16x32_f16(ah[tt][1], bh1, d, 0, 0, 0);
                d = __builtin_amdgcn_mfma_f32_16x16x32_f16(ah[tt][0], bl0, d, 0, 0, 0);
                d = __builtin_amdgcn_mfma_f32_16x16x32_f16(ah[tt][1], bl1, d, 0, 0, 0);
                d = __builtin_amdgcn_mfma_f32_16x16x32_f16(al[tt][0], bh0, d, 0, 0, 0);
                d = __builtin_amdgcn_mfma_f32_16x16x32_f16(al[tt][1], bh1, d, 0, 0, 0);
                #pragma unroll
                for (int ri = 0; ri < 4; ++ri) {
                    float dot = d[ri];
                    float cs  = dot * nri[tt][ri] * nmi;
                    float d2  = fmaxf(sq_r[tt][ri] + sqm - 2.f * dot, 0.f);
                    float dn  = sqrtf(d2);
                    float a   = __expf(cs - dn * __fdividef(1.f, nr[tt][ri] + nm + EPS));
                    att[ct][tt][ri] = a;
                    rs[tt][ri] += a;
                }
            }
        }
        // row-sum: reduce across the 16 lanes of each group (covers this wave's 64 cols)
        #pragma unroll
        for (int tt = 0; tt < 2; ++tt)
            #pragma unroll
            for (int ri = 0; ri < 4; ++ri) {
                float v = rs[tt][ri];
                v += __shfl_xor(v, 1);
                v += __shfl_xor(v, 2);
                v += __shfl_xor(v, 4);
                v += __shfl_xor(v, 8);
                rs[tt][ri] = v;
            }
        if (l15 == 0) {
            #pragma unroll
            for (int tt = 0; tt < 2; ++tt)
                #pragma unroll
                for (int ri = 0; ri < 4; ++ri)
                    rs_s[p][w][tt * 16 + g * 4 + ri] = rs[tt][ri];
        }
        __syncthreads();
        #pragma unroll
        for (int tt = 0; tt < 2; ++tt)
            #pragma unroll
            for (int ri = 0; ri < 4; ++ri) {
                int rl = tt * 16 + g * 4 + ri;
                float tot = 0.f;
                #pragma unroll
                for (int ww = 0; ww < 8; ++ww) tot += rs_s[p][ww][rl];
                float rinv = __fdividef(1.f, tot + EPS);
                #pragma unroll
                for (int ct = 0; ct < 4; ++ct)
                    acc[ct][tt][ri] += att[ct][tt][ri] * rinv;
            }
    }

    #pragma unroll
    for (int tt = 0; tt < 2; ++tt)
        #pragma unroll
        for (int ri = 0; ri < 4; ++ri) {
            const size_t ob = ((size_t)t * NN + n0 + tt * 16 + g * 4 + ri) * NN + w * 64 + l15;
            #pragma unroll
            for (int ct = 0; ct < 4; ++ct)
                out[ob + ct * 16] = acc[ct][tt][ri] * 0.125f;
        }
}

extern "C" void kernel_launch(void* const* d_in, const int* in_sizes, int n_in,
                              void* d_out, int out_size, void* d_ws, size_t ws_size,
                              hipStream_t stream) {
    const float* x    = (const float*)d_in[0];
    const float* W    = (const float*)d_in[1];
    const float* bias = (const float*)d_in[2];
    float* out = (float*)d_out;

    // ws layout: zh fp16 (16.78MB) | zl fp16 (16.78MB) | sq fp32 (0.52MB) | nv fp32 (0.52MB)
    const size_t ZELEMS = (size_t)BB * TT * NN * DD;   // 8388608
    _Float16* zh = (_Float16*)d_ws;
    _Float16* zl = zh + ZELEMS;
    float* sqv = (float*)(zh + 2 * ZELEMS);
    float* nvv = sqv + (size_t)BB * TT * NN;

    z_kernel<<<dim3(BB * (NN / 4)), dim3(256), 100352, stream>>>(x, W, bias, zh, zl, sqv, nvv);
    att2_kernel<<<dim3(TT * (NN / 32)), dim3(512), 0, stream>>>(zh, zl, sqv, nvv, out);
}

// Round 3
// 183.648 us; speedup vs baseline: 3.1387x; 1.3262x over previous
//
#include <hip/hip_runtime.h>
#include <math.h>

#define BB 8
#define NN 512
#define FF 128
#define TT 32
#define DD 64
constexpr float EPS = 1e-6f;

typedef _Float16 half8 __attribute__((ext_vector_type(8)));
typedef float f32x4 __attribute__((ext_vector_type(4)));

__device__ __forceinline__ float fast_tanh(float v) {
    // tanh(v) = 1 - 2/(exp(2v)+1); __expf handles overflow (inf -> 0) gracefully
    float e = __expf(2.f * v);
    return 1.f - 2.f * __builtin_amdgcn_rcpf(e + 1.f);
}

// ---------------- Stage 1: z = tanh(x @ W^T + b) -> fp16 hi/lo split in k-octet-major layout ----------------
// z layout: [b][t][ko][n][8] where ko = d>>3  (plane NN*DD elems per (b,t))
// grid: B * (N/2) = 2048 blocks, 256 threads
__global__ __launch_bounds__(256) void z_kernel(const float* __restrict__ x,
                                                const float* __restrict__ W,
                                                const float* __restrict__ bias,
                                                _Float16* __restrict__ zh,
                                                _Float16* __restrict__ zl,
                                                float* __restrict__ sqv,
                                                float* __restrict__ nvv) {
    extern __shared__ float lds[];
    float* xs = lds;                      // 2*32*132 = 8448 floats
    float* Wt = lds + 2 * 32 * 132;       // 128*64 = 8192 floats
    const int tid = threadIdx.x;
    const int b  = blockIdx.x >> 8;
    const int n0 = (blockIdx.x & 255) * 2;

    // W[64][128] -> Wt[f][d]
    const float4* W4 = (const float4*)W;
    #pragma unroll
    for (int it = 0; it < 8; ++it) {
        int idx4 = tid + it * 256;
        float4 w = W4[idx4];
        int d = idx4 >> 5;
        int f = (idx4 & 31) * 4;
        Wt[(f + 0) * 64 + d] = w.x;
        Wt[(f + 1) * 64 + d] = w.y;
        Wt[(f + 2) * 64 + d] = w.z;
        Wt[(f + 3) * 64 + d] = w.w;
    }
    // x[b][n0..n0+1][F][T] (8192 floats) -> xs[ns][t][f] (padded stride 132)
    const float4* x4 = (const float4*)(x + ((size_t)b * NN + n0) * FF * TT);
    #pragma unroll
    for (int it = 0; it < 8; ++it) {
        int idx4 = tid + it * 256;
        float4 v = x4[idx4];
        int e   = idx4 * 4;
        int ns  = e >> 12;
        int rem = e & 4095;
        int f   = rem >> 5;
        int t   = rem & 31;
        float* base = xs + ns * (32 * 132) + t * 132 + f;
        base[0 * 132] = v.x;
        base[1 * 132] = v.y;
        base[2 * 132] = v.z;
        base[3 * 132] = v.w;
    }
    __syncthreads();

    const int t  = tid >> 3;
    const int dg = tid & 7;
    const int d0 = dg * 8;
    float acc[2][8];
    #pragma unroll
    for (int ns = 0; ns < 2; ++ns)
        #pragma unroll
        for (int dd = 0; dd < 8; ++dd) acc[ns][dd] = 0.f;

    #pragma unroll 4
    for (int fc = 0; fc < FF; fc += 4) {
        float wv[4][8];
        #pragma unroll
        for (int k = 0; k < 4; ++k) {
            float4 a = *(const float4*)&Wt[(fc + k) * 64 + d0];
            float4 c = *(const float4*)&Wt[(fc + k) * 64 + d0 + 4];
            wv[k][0] = a.x; wv[k][1] = a.y; wv[k][2] = a.z; wv[k][3] = a.w;
            wv[k][4] = c.x; wv[k][5] = c.y; wv[k][6] = c.z; wv[k][7] = c.w;
        }
        #pragma unroll
        for (int ns = 0; ns < 2; ++ns) {
            float4 xv = *(const float4*)&xs[ns * (32 * 132) + t * 132 + fc];
            float xk[4] = {xv.x, xv.y, xv.z, xv.w};
            #pragma unroll
            for (int dd = 0; dd < 8; ++dd) {
                acc[ns][dd] += xk[0] * wv[0][dd] + xk[1] * wv[1][dd]
                             + xk[2] * wv[2][dd] + xk[3] * wv[3][dd];
            }
        }
    }

    float bb[8];
    #pragma unroll
    for (int dd = 0; dd < 8; ++dd) bb[dd] = bias[d0 + dd];

    const size_t planebase = ((size_t)b * TT + t) * NN * DD;   // start of [b][t] plane
    const size_t rowbase   = ((size_t)b * TT + t) * NN + n0;   // sq/nv index base
    float sqp[2];
    #pragma unroll
    for (int ns = 0; ns < 2; ++ns) {
        half8 hv, lv;
        float sp = 0.f;
        #pragma unroll
        for (int dd = 0; dd < 8; ++dd) {
            float zf = fast_tanh(acc[ns][dd] + bb[dd]);
            sp += zf * zf;
            _Float16 h = (_Float16)zf;
            hv[dd] = h;
            lv[dd] = (_Float16)(zf - (float)h);
        }
        size_t off = planebase + ((size_t)dg * NN + (n0 + ns)) * 8;
        *(half8*)(zh + off) = hv;
        *(half8*)(zl + off) = lv;
        sqp[ns] = sp;
    }
    // reduce sq over the 8 d-group lanes (consecutive lanes)
    #pragma unroll
    for (int k = 1; k < 8; k <<= 1) {
        #pragma unroll
        for (int ns = 0; ns < 2; ++ns) sqp[ns] += __shfl_xor(sqp[ns], k);
    }
    if (dg == 0) {
        #pragma unroll
        for (int ns = 0; ns < 2; ++ns) {
            sqv[rowbase + ns] = sqp[ns];
            nvv[rowbase + ns] = sqrtf(sqp[ns]) + EPS;
        }
    }
}

// ---------------- Stage 2: S = Z Z^T via split-fp16 MFMA, epilogue, normalize, mean over b ----------------
// grid: 1024 blocks (t = bid&31, rowtile16 = bid>>5), 256 threads = 4 waves.
// wave w: rows n0..n0+15 (1 tile), cols w*128..w*128+127 (8 col-tiles).
__global__ __launch_bounds__(256, 3) void att3_kernel(const _Float16* __restrict__ zh,
                                                      const _Float16* __restrict__ zl,
                                                      const float* __restrict__ sqv,
                                                      const float* __restrict__ nvv,
                                                      float* __restrict__ out) {
    __shared__ float nv_s[2][NN];
    __shared__ float sq_s[2][NN];
    __shared__ float rs_s[2][4][16];
    const int tid  = threadIdx.x;
    const int w    = tid >> 6;
    const int lane = tid & 63;
    const int l15  = lane & 15;
    const int g    = lane >> 4;
    const int t    = blockIdx.x & 31;
    const int n0   = (blockIdx.x >> 5) * 16;

    float acc[8][4];
    #pragma unroll
    for (int ct = 0; ct < 8; ++ct)
        #pragma unroll
        for (int ri = 0; ri < 4; ++ri) acc[ct][ri] = 0.f;

    for (int b = 0; b < BB; ++b) {
        const int p = b & 1;
        const size_t nbase = ((size_t)b * TT + t) * NN;
        const size_t slab  = nbase * DD;
        nv_s[p][tid]       = nvv[nbase + tid];
        nv_s[p][tid + 256] = nvv[nbase + tid + 256];
        sq_s[p][tid]       = sqv[nbase + tid];
        sq_s[p][tid + 256] = sqv[nbase + tid + 256];

        const _Float16* zhp = zh + slab;
        const _Float16* zlp = zl + slab;

        // A fragments: rows n0+l15, k = s*32 + g*8 + i  -> plane ko = s*4+g
        half8 ah[2], al[2];
        #pragma unroll
        for (int s = 0; s < 2; ++s) {
            const size_t ro = ((size_t)(s * 4 + g) * NN + n0 + l15) * 8;
            ah[s] = *(const half8*)(zhp + ro);
            al[s] = *(const half8*)(zlp + ro);
        }
        __syncthreads();

        float nr[4], sq_r[4], nri[4];
        #pragma unroll
        for (int ri = 0; ri < 4; ++ri) {
            int row = n0 + g * 4 + ri;
            nr[ri]   = nv_s[p][row];
            sq_r[ri] = sq_s[p][row];
            nri[ri]  = __builtin_amdgcn_rcpf(nr[ri]);
        }

        float att[8][4];
        float rs[4] = {0.f, 0.f, 0.f, 0.f};

        // depth-1 prefetch pipeline over 8 col-tiles
        half8 bh0c, bh1c, bl0c, bl1c;
        {
            const size_t c0 = ((size_t)(0 * 4 + g) * NN + w * 128 + l15) * 8;
            const size_t c1 = ((size_t)(1 * 4 + g) * NN + w * 128 + l15) * 8;
            bh0c = *(const half8*)(zhp + c0);
            bh1c = *(const half8*)(zhp + c1);
            bl0c = *(const half8*)(zlp + c0);
            bl1c = *(const half8*)(zlp + c1);
        }
        #pragma unroll
        for (int ct = 0; ct < 8; ++ct) {
            half8 bh0n, bh1n, bl0n, bl1n;
            if (ct < 7) {
                const size_t c0 = ((size_t)(0 * 4 + g) * NN + w * 128 + (ct + 1) * 16 + l15) * 8;
                const size_t c1 = ((size_t)(1 * 4 + g) * NN + w * 128 + (ct + 1) * 16 + l15) * 8;
                bh0n = *(const half8*)(zhp + c0);
                bh1n = *(const half8*)(zhp + c1);
                bl0n = *(const half8*)(zlp + c0);
                bl1n = *(const half8*)(zlp + c1);
            }
            f32x4 d = {0.f, 0.f, 0.f, 0.f};
            d = __builtin_amdgcn_mfma_f32_16x16x32_f16(ah[0], bh0c, d, 0, 0, 0);
            d = __builtin_amdgcn_mfma_f32_16x16x32_f16(ah[1], bh1c, d, 0, 0, 0);
            d = __builtin_amdgcn_mfma_f32_16x16x32_f16(ah[0], bl0c, d, 0, 0, 0);
            d = __builtin_amdgcn_mfma_f32_16x16x32_f16(ah[1], bl1c, d, 0, 0, 0);
            d = __builtin_amdgcn_mfma_f32_16x16x32_f16(al[0], bh0c, d, 0, 0, 0);
            d = __builtin_amdgcn_mfma_f32_16x16x32_f16(al[1], bh1c, d, 0, 0, 0);

            const int col = w * 128 + ct * 16 + l15;
            float nm  = nv_s[p][col];
            float sqm = sq_s[p][col];
            float nmi = __builtin_amdgcn_rcpf(nm);
            #pragma unroll
            for (int ri = 0; ri < 4; ++ri) {
                float dot = d[ri];
                float cs  = dot * nri[ri] * nmi;
                float d2  = fmaxf(sq_r[ri] + sqm - 2.f * dot, 0.f);
                float dn  = __builtin_amdgcn_sqrtf(d2);
                float a   = __expf(cs - dn * __builtin_amdgcn_rcpf(nr[ri] + nm + EPS));
                att[ct][ri] = a;
                rs[ri] += a;
            }
            bh0c = bh0n; bh1c = bh1n; bl0c = bl0n; bl1c = bl1n;
        }

        // row-sum across the 16 lanes of each group (covers this wave's 128 cols)
        #pragma unroll
        for (int ri = 0; ri < 4; ++ri) {
            float v = rs[ri];
            v += __shfl_xor(v, 1);
            v += __shfl_xor(v, 2);
            v += __shfl_xor(v, 4);
            v += __shfl_xor(v, 8);
            rs[ri] = v;
        }
        if (l15 == 0) {
            #pragma unroll
            for (int ri = 0; ri < 4; ++ri)
                rs_s[p][w][g * 4 + ri] = rs[ri];
        }
        __syncthreads();
        #pragma unroll
        for (int ri = 0; ri < 4; ++ri) {
            int rl = g * 4 + ri;
            float tot = rs_s[p][0][rl] + rs_s[p][1][rl] + rs_s[p][2][rl] + rs_s[p][3][rl];
            float rinv = __builtin_amdgcn_rcpf(tot + EPS);
            #pragma unroll
            for (int ct = 0; ct < 8; ++ct)
                acc[ct][ri] += att[ct][ri] * rinv;
        }
    }

    // write out[t][n0+g*4+ri][w*128 + ct*16 + l15]
    #pragma unroll
    for (int ri = 0; ri < 4; ++ri) {
        const size_t ob = ((size_t)t * NN + n0 + g * 4 + ri) * NN + w * 128 + l15;
        #pragma unroll
        for (int ct = 0; ct < 8; ++ct)
            out[ob + ct * 16] = acc[ct][ri] * 0.125f;
    }
}

extern "C" void kernel_launch(void* const* d_in, const int* in_sizes, int n_in,
                              void* d_out, int out_size, void* d_ws, size_t ws_size,
                              hipStream_t stream) {
    const float* x    = (const float*)d_in[0];
    const float* W    = (const float*)d_in[1];
    const float* bias = (const float*)d_in[2];
    float* out = (float*)d_out;

    const size_t ZELEMS = (size_t)BB * TT * NN * DD;   // 8388608
    _Float16* zh = (_Float16*)d_ws;
    _Float16* zl = zh + ZELEMS;
    float* sqv = (float*)(zh + 2 * ZELEMS);
    float* nvv = sqv + (size_t)BB * TT * NN;

    // Stage 1: (2*32*132 + 8192)*4 = 66560 B dynamic LDS, 2 blocks/CU
    z_kernel<<<dim3(BB * (NN / 2)), dim3(256), 66560, stream>>>(x, W, bias, zh, zl, sqv, nvv);
    // Stage 2
    att3_kernel<<<dim3(TT * (NN / 16)), dim3(256), 0, stream>>>(zh, zl, sqv, nvv, out);
}